// Round 4
// baseline (1717.928 us; speedup 1.0000x reference)
//
#include <hip/hip_runtime.h>
#include <hip/hip_bf16.h>
#include <cstdint>
#include <cstddef>

#define DIM 5120
#define NH 40
#define HD 128
#define S_LEN 4096
#define L_LEN 512
#define CBATCH 2            // 2*B (cond + uncond)
#define MQ (CBATCH*S_LEN)   // 8192 rows of hidden
#define ML (CBATCH*L_LEN)   // 1024 rows of context

typedef unsigned short ushort_t;
typedef __bf16 bf16x8 __attribute__((ext_vector_type(8)));
typedef float f32x4 __attribute__((ext_vector_type(4)));
typedef float f32x16 __attribute__((ext_vector_type(16)));

__device__ __forceinline__ ushort_t f2bf(float f) {
  union { float f; unsigned u; } c; c.f = f;
  unsigned r = c.u + 0x7fffu + ((c.u >> 16) & 1u);
  return (ushort_t)(r >> 16);
}

__device__ __forceinline__ void load_lds16(const void* g, void* l) {
  __builtin_amdgcn_global_load_lds(
      (const __attribute__((address_space(1))) void*)g,
      (__attribute__((address_space(3))) void*)l, 16, 0, 0);
}

// ---------------- fp32 -> bf16 convert ----------------
__global__ __launch_bounds__(256) void cvt_f32_bf16(const float* __restrict__ in,
                                                    ushort_t* __restrict__ out, int n4) {
  int i = blockIdx.x * 256 + threadIdx.x;
  if (i >= n4) return;
  float4 v = *(const float4*)(in + 4ull * (size_t)i);
  ushort4 o;
  o.x = f2bf(v.x); o.y = f2bf(v.y); o.z = f2bf(v.z); o.w = f2bf(v.w);
  *(ushort4*)(out + 4ull * (size_t)i) = o;
}

// ============ 256x128 8-phase GEMM: C[M,N] = A[M,K] @ W[N,K]^T + bias ============
// BM=256, BN=128, BK=64 (two 32-slabs); 8 waves as 4Mx2N (wave tile 64x64).
// LDS: 3 tile-buffers x 48 KiB = 144 KiB; tile = [B-s0 8K][A-s0 16K][B-s1 8K][A-s1 16K].
// During tile t both halves of tile t+2 are staged (distinct buffer -> no hazard);
// tile-end vmcnt(6) proves tile t+1 landed. st_16x32 swizzle via pre-swizzled source.
template <int OUT_F32>
__global__ __launch_bounds__(512, 2) void gemm_bt8(const ushort_t* __restrict__ A,
                                                   const ushort_t* __restrict__ W,
                                                   const float* __restrict__ bias,
                                                   void* __restrict__ Cout,
                                                   int M, int N, int K) {
  __shared__ ushort_t lds[73728];   // 144 KiB
  char* ldsc = (char*)lds;
  const int tid = threadIdx.x;
  const int lane = tid & 63, w = tid >> 6;
  const int g = lane >> 4, c = lane & 15;
  const int wm = w >> 1, wn = w & 1;
  const int ntn = N >> 7;
  const int nwg = gridDim.x;
  int bid = blockIdx.x;
  bid = (bid & 7) * (nwg >> 3) + (bid >> 3);   // XCD swizzle (nwg % 8 == 0)
  const int tm = bid / ntn, tn = bid % ntn;
  const size_t m0 = (size_t)tm * 256, n0 = (size_t)tn * 128;
  const ushort_t* Ab = A + m0 * (size_t)K;
  const ushort_t* Bb = W + n0 * (size_t)K;
  const int NT = K >> 6;

  // staging: linear LDS dest, inverse-swizzled global source
  const int srow = tid >> 2;
  const int sgq  = (tid & 3) ^ (((tid >> 5) & 1) << 1);
  const size_t sRB = (size_t)srow * K + (size_t)sgq * 8;   // rows 0-127 of region
  const size_t sRA1 = sRB + (size_t)128 * K;               // A rows 128-255
  const int d0 = tid * 16;

  // ds_read byte offsets within a k-slab half (swizzled)
  int offA[4], offB[4];
#pragma unroll
  for (int m = 0; m < 4; ++m) {
    int row = wm * 64 + m * 16 + c;
    offA[m] = 8192 + row * 64 + ((g * 16) ^ ((row & 8) << 2));
  }
#pragma unroll
  for (int n = 0; n < 4; ++n) {
    int row = wn * 64 + n * 16 + c;
    offB[n] = row * 64 + ((g * 16) ^ ((row & 8) << 2));
  }

  auto STAGE = [&](int tileIdx, int slab, int bufbase) {
    const size_t kof = (size_t)tileIdx * 64 + (size_t)(slab << 5);
    char* db = ldsc + bufbase + slab * 24576;
    load_lds16(Bb + sRB + kof,  db + d0);            // B rows 0-127
    load_lds16(Ab + sRB + kof,  db + 8192 + d0);     // A rows 0-127
    load_lds16(Ab + sRA1 + kof, db + 16384 + d0);    // A rows 128-255
  };

  f32x4 acc[4][4] = {};

  // prologue: tiles 0 and 1
  STAGE(0, 0, 0); STAGE(0, 1, 0);
  STAGE(1, 0, 49152); STAGE(1, 1, 49152);
  asm volatile("s_waitcnt vmcnt(6)" ::: "memory");   // tile 0 landed
  __builtin_amdgcn_s_barrier();

  int rb = 0, sb = 2 * 49152;
  for (int t = 0; t < NT; ++t) {
    bf16x8 a[4], b[4];
    // ---- phase p0: k-slab 0
#pragma unroll
    for (int m = 0; m < 4; ++m) a[m] = *(const bf16x8*)(ldsc + rb + offA[m]);
#pragma unroll
    for (int n = 0; n < 4; ++n) b[n] = *(const bf16x8*)(ldsc + rb + offB[n]);
    if (t < NT - 2) STAGE(t + 2, 0, sb);
    __builtin_amdgcn_s_barrier();
    asm volatile("s_waitcnt lgkmcnt(0)" ::: "memory");
    __builtin_amdgcn_sched_barrier(0);
    __builtin_amdgcn_s_setprio(1);
#pragma unroll
    for (int m = 0; m < 4; ++m)
#pragma unroll
      for (int n = 0; n < 4; ++n)
        acc[m][n] = __builtin_amdgcn_mfma_f32_16x16x32_bf16(a[m], b[n], acc[m][n], 0, 0, 0);
    __builtin_amdgcn_s_setprio(0);
    __builtin_amdgcn_s_barrier();
    // ---- phase p1: k-slab 1
#pragma unroll
    for (int m = 0; m < 4; ++m) a[m] = *(const bf16x8*)(ldsc + rb + 24576 + offA[m]);
#pragma unroll
    for (int n = 0; n < 4; ++n) b[n] = *(const bf16x8*)(ldsc + rb + 24576 + offB[n]);
    if (t < NT - 2) STAGE(t + 2, 1, sb);
    __builtin_amdgcn_s_barrier();
    asm volatile("s_waitcnt lgkmcnt(0)" ::: "memory");
    __builtin_amdgcn_sched_barrier(0);
    __builtin_amdgcn_s_setprio(1);
#pragma unroll
    for (int m = 0; m < 4; ++m)
#pragma unroll
      for (int n = 0; n < 4; ++n)
        acc[m][n] = __builtin_amdgcn_mfma_f32_16x16x32_bf16(a[m], b[n], acc[m][n], 0, 0, 0);
    __builtin_amdgcn_s_setprio(0);
    // tile-end: prove tile t+1 landed before crossing into it
    if (t < NT - 2)       asm volatile("s_waitcnt vmcnt(6)" ::: "memory");
    else if (t == NT - 2) asm volatile("s_waitcnt vmcnt(0)" ::: "memory");
    __builtin_amdgcn_s_barrier();
    rb += 49152; if (rb == 147456) rb = 0;
    sb += 49152; if (sb == 147456) sb = 0;
  }

  // epilogue: C/D layout col=lane&15, row=(lane>>4)*4+reg
#pragma unroll
  for (int m = 0; m < 4; ++m) {
#pragma unroll
    for (int n = 0; n < 4; ++n) {
      size_t gm = m0 + wm * 64 + m * 16 + g * 4;
      size_t gn = n0 + wn * 64 + n * 16 + c;
      float bn = bias[gn];
#pragma unroll
      for (int r = 0; r < 4; ++r) {
        float v = acc[m][n][r] + bn;
        if (OUT_F32) ((float*)Cout)[(gm + r) * (size_t)N + gn] = v;
        else         ((ushort_t*)Cout)[(gm + r) * (size_t)N + gn] = f2bf(v);
      }
    }
  }
  (void)M;
}

// ---------------- 128x128 GEMM (m97 structure) for the small KV GEMM ----------------
template <int OUT_F32>
__global__ __launch_bounds__(256) void gemm_bt(const ushort_t* __restrict__ A,
                                               const ushort_t* __restrict__ W,
                                               const float* __restrict__ bias,
                                               void* __restrict__ Cout,
                                               int M, int N, int K) {
  __shared__ ushort_t sA[128 * 32];
  __shared__ ushort_t sB[128 * 32];
  const int tid = threadIdx.x;
  const int w = tid >> 6, lane = tid & 63;
  const int g = lane >> 4, c = lane & 15;
  const int ntn = N >> 7;
  const int nwg = gridDim.x;
  int bid = blockIdx.x;
  bid = (bid & 7) * (nwg >> 3) + (bid >> 3);
  const int tm = bid / ntn, tn = bid % ntn;
  const size_t m0 = (size_t)tm * 128, n0 = (size_t)tn * 128;
  const int wr = (w >> 1) * 64, wc = (w & 1) * 64;

  f32x4 acc[4][4] = {};

  const ushort_t* Abase = A + m0 * (size_t)K;
  const ushort_t* Bbase = W + n0 * (size_t)K;

  for (int k0 = 0; k0 < K; k0 += 32) {
    __syncthreads();
#pragma unroll
    for (int i = 0; i < 2; ++i) {
      int gid = i * 256 + tid;
      int row = gid >> 2, colE = (gid & 3) << 3;
      load_lds16(Abase + (size_t)row * K + k0 + colE, sA + i * 2048 + w * 512);
      load_lds16(Bbase + (size_t)row * K + k0 + colE, sB + i * 2048 + w * 512);
    }
    __syncthreads();
    bf16x8 a[4], b[4];
#pragma unroll
    for (int m = 0; m < 4; ++m)
      a[m] = *(const bf16x8*)(sA + (wr + m * 16 + c) * 32 + g * 8);
#pragma unroll
    for (int n = 0; n < 4; ++n)
      b[n] = *(const bf16x8*)(sB + (wc + n * 16 + c) * 32 + g * 8);
#pragma unroll
    for (int m = 0; m < 4; ++m)
#pragma unroll
      for (int n = 0; n < 4; ++n)
        acc[m][n] = __builtin_amdgcn_mfma_f32_16x16x32_bf16(a[m], b[n], acc[m][n], 0, 0, 0);
  }

#pragma unroll
  for (int m = 0; m < 4; ++m) {
#pragma unroll
    for (int n = 0; n < 4; ++n) {
      size_t gm = m0 + wr + m * 16 + g * 4;
      size_t gn = n0 + wc + n * 16 + c;
      float bn = bias[gn];
#pragma unroll
      for (int r = 0; r < 4; ++r) {
        float v = acc[m][n][r] + bn;
        if (OUT_F32) ((float*)Cout)[(gm + r) * (size_t)N + gn] = v;
        else         ((ushort_t*)Cout)[(gm + r) * (size_t)N + gn] = f2bf(v);
      }
    }
  }
}

// ---------------- RMSNorm (in place; optional extra output scale) ----------------
__global__ __launch_bounds__(256) void rmsnorm_rows(ushort_t* __restrict__ x,
                                                    const float* __restrict__ gw,
                                                    int ncols, int stride, float oscale) {
  const int row = blockIdx.x;
  ushort_t* p = x + (size_t)row * stride;
  const int tid = threadIdx.x;
  const int nch = ncols >> 3;
  float ss = 0.f;
  for (int ci = tid; ci < nch; ci += 256) {
    bf16x8 v = *(const bf16x8*)(p + ci * 8);
#pragma unroll
    for (int j = 0; j < 8; ++j) { float f = (float)v[j]; ss += f * f; }
  }
#pragma unroll
  for (int off = 1; off < 64; off <<= 1) ss += __shfl_xor(ss, off);
  __shared__ float sred[4];
  if ((tid & 63) == 0) sred[tid >> 6] = ss;
  __syncthreads();
  float tot = sred[0] + sred[1] + sred[2] + sred[3];
  float inv = rsqrtf(tot / (float)ncols + 1e-6f) * oscale;
  for (int ci = tid; ci < nch; ci += 256) {
    bf16x8 v = *(const bf16x8*)(p + ci * 8);
    bf16x8 ov;
#pragma unroll
    for (int j = 0; j < 8; ++j) {
      float f = (float)v[j];
      ushort_t ob = f2bf(f * inv * gw[ci * 8 + j]);
      ov[j] = *(__bf16*)&ob;
    }
    *(bf16x8*)(p + ci * 8) = ov;
  }
}

// ---------------- V transpose: kv[:, DIM + h*HD + d] -> vt[bh][d][l] ----------------
__global__ __launch_bounds__(256) void transpose_v(const ushort_t* __restrict__ kv,
                                                   ushort_t* __restrict__ vt) {
  const int bh = blockIdx.y, b = bh / NH, h = bh % NH;
  const int l0 = blockIdx.x * 32;
  const ushort_t* src = kv + (size_t)b * L_LEN * (2 * DIM) + DIM + (size_t)h * HD;
  ushort_t* dst = vt + (size_t)bh * HD * L_LEN;
  __shared__ ushort_t tile[32][HD + 16];
  const int tid = threadIdx.x;
#pragma unroll
  for (int i = 0; i < 2; ++i) {
    int gid = i * 256 + tid;
    int r = gid >> 4, ce = (gid & 15) << 3;
    *(bf16x8*)(&tile[r][ce]) = *(const bf16x8*)(src + (size_t)(l0 + r) * (2 * DIM) + ce);
  }
  __syncthreads();
#pragma unroll
  for (int i = 0; i < 2; ++i) {
    int gid = i * 256 + tid;
    int d = gid >> 2, le = (gid & 3) << 3;
    bf16x8 v;
#pragma unroll
    for (int j = 0; j < 8; ++j) v[j] = *(__bf16*)&tile[le + j][d];
    *(bf16x8*)(dst + (size_t)d * L_LEN + l0 + le) = v;
  }
}

// ---------------- fused cross-attention (swapped-QK^T, in-register softmax) ----------
__global__ __launch_bounds__(256) void attn_fwd(const ushort_t* __restrict__ q,
                                                const ushort_t* __restrict__ kv,
                                                const ushort_t* __restrict__ vt,
                                                ushort_t* __restrict__ out) {
  const int bh = blockIdx.y, b = bh / NH, h = bh % NH;
  const int tid = threadIdx.x, w = tid >> 6, lane = tid & 63;
  const int lq = lane & 31, hi = lane >> 5;
  const int qr0 = blockIdx.x * 128 + w * 32;

  const ushort_t* qrow  = q  + ((size_t)b * S_LEN + qr0 + lq) * DIM + (size_t)h * HD + hi * 8;
  const ushort_t* krow  = kv + (size_t)b * L_LEN * (2 * DIM) + (size_t)h * HD
                             + (size_t)lq * (2 * DIM) + hi * 8;
  const ushort_t* vrow  = vt + (size_t)bh * HD * L_LEN + (size_t)lq * L_LEN + hi * 8;

  bf16x8 qf[8];
#pragma unroll
  for (int ks = 0; ks < 8; ++ks) qf[ks] = *(const bf16x8*)(qrow + ks * 16);

  f32x16 o[4];
#pragma unroll
  for (int ch = 0; ch < 4; ++ch) o[ch] = 0.f;
  float m = -1e30f, lsum = 0.f;

  for (int l0 = 0; l0 < L_LEN; l0 += 32) {
    f32x16 sv = 0.f;
#pragma unroll
    for (int ks = 0; ks < 8; ++ks) {
      bf16x8 kf = *(const bf16x8*)(krow + (size_t)l0 * (2 * DIM) + ks * 16);
      sv = __builtin_amdgcn_mfma_f32_32x32x16_bf16(kf, qf[ks], sv, 0, 0, 0);
    }
    float pm = fmaxf(fmaxf(fmaxf(sv[0], sv[1]), fmaxf(sv[2], sv[3])),
                     fmaxf(fmaxf(sv[4], sv[5]), fmaxf(sv[6], sv[7])));
    pm = fmaxf(pm, fmaxf(fmaxf(fmaxf(sv[8], sv[9]), fmaxf(sv[10], sv[11])),
                         fmaxf(fmaxf(sv[12], sv[13]), fmaxf(sv[14], sv[15]))));
    pm = fmaxf(pm, __shfl_xor(pm, 32));
    if (__ballot(pm > m + 8.0f)) {
      float mn = fmaxf(m, pm);
      float al = __builtin_amdgcn_exp2f(m - mn);
      lsum *= al;
      m = mn;
#pragma unroll
      for (int r = 0; r < 16; ++r) {
        float ar = __shfl(al, (r & 3) + 8 * (r >> 2) + 4 * hi);
        o[0][r] *= ar; o[1][r] *= ar; o[2][r] *= ar; o[3][r] *= ar;
      }
    }
    float p[16]; float ls = 0.f;
#pragma unroll
    for (int r = 0; r < 16; ++r) { p[r] = __builtin_amdgcn_exp2f(sv[r] - m); ls += p[r]; }
    ls += __shfl_xor(ls, 32);
    lsum += ls;
    bf16x8 pa[2];
#pragma unroll
    for (int ks = 0; ks < 2; ++ks) {
      unsigned w0 = (unsigned)f2bf(p[8 * ks + 0]) | ((unsigned)f2bf(p[8 * ks + 1]) << 16);
      unsigned w1 = (unsigned)f2bf(p[8 * ks + 2]) | ((unsigned)f2bf(p[8 * ks + 3]) << 16);
      unsigned w2 = (unsigned)f2bf(p[8 * ks + 4]) | ((unsigned)f2bf(p[8 * ks + 5]) << 16);
      unsigned w3 = (unsigned)f2bf(p[8 * ks + 6]) | ((unsigned)f2bf(p[8 * ks + 7]) << 16);
      unsigned e0 = __shfl_xor((int)w0, 32), e1 = __shfl_xor((int)w1, 32);
      unsigned e2 = __shfl_xor((int)w2, 32), e3 = __shfl_xor((int)w3, 32);
      unsigned d0 = hi ? e2 : w0, d1 = hi ? e3 : w1;
      unsigned d2 = hi ? w2 : e0, d3 = hi ? w3 : e1;
      unsigned tmp[4] = {d0, d1, d2, d3};
      pa[ks] = *(const bf16x8*)tmp;
    }
#pragma unroll
    for (int ch = 0; ch < 4; ++ch) {
#pragma unroll
      for (int ks = 0; ks < 2; ++ks) {
        bf16x8 vf = *(const bf16x8*)(vrow + (size_t)ch * 32 * L_LEN + l0 + ks * 16);
        o[ch] = __builtin_amdgcn_mfma_f32_32x32x16_bf16(pa[ks], vf, o[ch], 0, 0, 0);
      }
    }
  }

  float inv[16];
#pragma unroll
  for (int r = 0; r < 16; ++r) {
    float lr = __shfl(lsum, (r & 3) + 8 * (r >> 2) + 4 * hi);
    inv[r] = 1.0f / lr;
  }
  ushort_t* ob = out + ((size_t)b * S_LEN + qr0) * DIM + (size_t)h * HD;
#pragma unroll
  for (int ch = 0; ch < 4; ++ch)
#pragma unroll
    for (int r = 0; r < 16; ++r) {
      int row = (r & 3) + 8 * (r >> 2) + 4 * hi;
      ob[(size_t)row * DIM + ch * 32 + lq] = f2bf(o[ch][r] * inv[r]);
    }
}

// ---------------- host ----------------
extern "C" void kernel_launch(void* const* d_in, const int* in_sizes, int n_in,
                              void* d_out, int out_size, void* d_ws, size_t ws_size,
                              hipStream_t stream) {
  (void)in_sizes; (void)n_in; (void)out_size; (void)ws_size;
  const float* hidden_c = (const float*)d_in[0];
  const float* hidden_u = (const float*)d_in[1];
  const float* ctx_c    = (const float*)d_in[2];
  const float* ctx_u    = (const float*)d_in[3];
  const float* Wq  = (const float*)d_in[4];
  const float* bq  = (const float*)d_in[5];
  const float* Wkv = (const float*)d_in[6];
  const float* bkv = (const float*)d_in[7];
  const float* gq  = (const float*)d_in[8];
  const float* gk  = (const float*)d_in[9];
  const float* Wo  = (const float*)d_in[10];
  const float* bo  = (const float*)d_in[11];

  char* ws = (char*)d_ws;
  size_t off = 0;
  auto alloc = [&](size_t bytes) {
    char* p = ws + off; off += (bytes + 255) & ~(size_t)255; return p;
  };
  ushort_t* hbf  = (ushort_t*)alloc((size_t)MQ * DIM * 2);
  ushort_t* cbf  = (ushort_t*)alloc((size_t)ML * DIM * 2);
  ushort_t* wqb  = (ushort_t*)alloc((size_t)DIM * DIM * 2);
  ushort_t* wkvb = (ushort_t*)alloc((size_t)2 * DIM * DIM * 2);
  ushort_t* kvb  = (ushort_t*)alloc((size_t)ML * 2 * DIM * 2);
  ushort_t* vtb  = (ushort_t*)alloc((size_t)CBATCH * NH * HD * L_LEN * 2);
  ushort_t* qb   = (ushort_t*)d_out;

  auto cvt = [&](const float* in, ushort_t* o, size_t n) {
    int n4 = (int)(n >> 2);
    cvt_f32_bf16<<<dim3((n4 + 255) / 256), dim3(256), 0, stream>>>(in, o, n4);
  };
  cvt(hidden_c, hbf, (size_t)S_LEN * DIM);
  cvt(hidden_u, hbf + (size_t)S_LEN * DIM, (size_t)S_LEN * DIM);
  cvt(ctx_c, cbf, (size_t)L_LEN * DIM);
  cvt(ctx_u, cbf + (size_t)L_LEN * DIM, (size_t)L_LEN * DIM);
  cvt(Wq, wqb, (size_t)DIM * DIM);
  cvt(Wkv, wkvb, (size_t)2 * DIM * DIM);

  // Q = hidden @ Wq^T + bq  (256x128 tiles, grid 32x40=1280 = 5/CU even)
  gemm_bt8<0><<<dim3((MQ / 256) * (DIM / 128)), dim3(512), 0, stream>>>(
      hbf, wqb, bq, (void*)qb, MQ, DIM, DIM);
  // KV = context @ Wkv^T + bkv   [128x128]
  gemm_bt<0><<<dim3((ML / 128) * ((2 * DIM) / 128)), dim3(256), 0, stream>>>(
      cbf, wkvb, bkv, (void*)kvb, ML, 2 * DIM, DIM);
  cvt(Wo, wqb, (size_t)DIM * DIM);

  const float qscale = 0.08838834764831845f * 1.4426950408889634f;
  rmsnorm_rows<<<dim3(MQ), dim3(256), 0, stream>>>(qb, gq, DIM, DIM, qscale);
  rmsnorm_rows<<<dim3(ML), dim3(256), 0, stream>>>(kvb, gk, DIM, 2 * DIM, 1.0f);
  transpose_v<<<dim3(L_LEN / 32, CBATCH * NH), dim3(256), 0, stream>>>(kvb, vtb);

  attn_fwd<<<dim3(S_LEN / 128, CBATCH * NH), dim3(256), 0, stream>>>(qb, kvb, vtb, hbf);

  // out = attn_out @ Wo^T + bo -> d_out (fp32)
  gemm_bt8<1><<<dim3((MQ / 256) * (DIM / 128)), dim3(512), 0, stream>>>(
      hbf, wqb, bo, d_out, MQ, DIM, DIM);
}

// Round 5
// 1598.189 us; speedup vs baseline: 1.0749x; 1.0749x over previous
//
#include <hip/hip_runtime.h>
#include <hip/hip_bf16.h>
#include <cstdint>
#include <cstddef>

#define DIM 5120
#define NH 40
#define HD 128
#define S_LEN 4096
#define L_LEN 512
#define CBATCH 2            // 2*B (cond + uncond)
#define MQ (CBATCH*S_LEN)   // 8192 rows of hidden
#define ML (CBATCH*L_LEN)   // 1024 rows of context

typedef unsigned short ushort_t;
typedef __bf16 bf16x8 __attribute__((ext_vector_type(8)));
typedef float f32x4 __attribute__((ext_vector_type(4)));
typedef float f32x16 __attribute__((ext_vector_type(16)));

__device__ __forceinline__ ushort_t f2bf(float f) {
  union { float f; unsigned u; } c; c.f = f;
  unsigned r = c.u + 0x7fffu + ((c.u >> 16) & 1u);
  return (ushort_t)(r >> 16);
}

__device__ __forceinline__ void load_lds16(const void* g, void* l) {
  __builtin_amdgcn_global_load_lds(
      (const __attribute__((address_space(1))) void*)g,
      (__attribute__((address_space(3))) void*)l, 16, 0, 0);
}

// ---------------- fp32 -> bf16 convert ----------------
__global__ __launch_bounds__(256) void cvt_f32_bf16(const float* __restrict__ in,
                                                    ushort_t* __restrict__ out, int n4) {
  int i = blockIdx.x * 256 + threadIdx.x;
  if (i >= n4) return;
  float4 v = *(const float4*)(in + 4ull * (size_t)i);
  ushort4 o;
  o.x = f2bf(v.x); o.y = f2bf(v.y); o.z = f2bf(v.z); o.w = f2bf(v.w);
  *(ushort4*)(out + 4ull * (size_t)i) = o;
}

// ============ 256x256 8-phase GEMM with 9-region LDS ring ============
// 8 waves (2M x 4N), BK=64 as two 32-slabs; 4 phases per K-tile, 16 MFMA each.
// LDS ring: 9 regions x 16 KiB = 144 KiB. Half-tile h -> region h%9.
// During tile t, phases p=0..3 issue tile (t+2)'s half p (distance 8 halves);
// tile-end vmcnt(6) proves tile t+1 landed (~4.5 phases of latency cover).
// st_16x32 swizzle: linear gload_lds dest + inverse-swizzled global source.
template <int OUT_F32>
__global__ __launch_bounds__(512, 2) void gemm_bt8(const ushort_t* __restrict__ A,
                                                   const ushort_t* __restrict__ W,
                                                   const float* __restrict__ bias,
                                                   void* __restrict__ Cout,
                                                   int M, int N, int K) {
  __shared__ ushort_t lds[73728];   // 144 KiB = 9 x 16 KiB
  char* ldsc = (char*)lds;
  const int tid = threadIdx.x;
  const int lane = tid & 63, w = tid >> 6;
  const int g = lane >> 4, c = lane & 15;
  const int wm = w >> 2, wn = w & 3;
  const int ntn = N >> 8;
  const int nwg = gridDim.x;
  int bid = blockIdx.x;
  bid = (bid & 7) * (nwg >> 3) + (bid >> 3);   // XCD swizzle (nwg % 8 == 0)
  const int tm = bid / ntn, tn = bid % ntn;
  const size_t m0 = (size_t)tm * 256, n0 = (size_t)tn * 256;
  const ushort_t* Ab = A + m0 * (size_t)K;
  const ushort_t* Bb = W + n0 * (size_t)K;
  const int NT = K >> 6;

  // staging: linear LDS dest, inverse-swizzled global source
  const int srow = tid >> 2;
  const int sgq  = (tid & 3) ^ (((tid >> 5) & 1) << 1);
  const size_t rb0 = (size_t)srow * K + (size_t)sgq * 8;   // rows 0-127
  const size_t rb1 = rb0 + (size_t)128 * K;                // rows 128-255
  const int d0 = tid * 16;

  // ds_read byte offsets within a region (swizzled); regions hold 256 rows x 32 cols
  int offA[8], offB[4];
#pragma unroll
  for (int m = 0; m < 8; ++m) {
    int row = wm * 128 + m * 16 + c;
    offA[m] = row * 64 + ((g * 16) ^ ((row & 8) << 2));
  }
#pragma unroll
  for (int n = 0; n < 4; ++n) {
    int row = wn * 64 + n * 16 + c;
    offB[n] = row * 64 + ((g * 16) ^ ((row & 8) << 2));
  }

  // half-tile j of tile tIdx: j = {B-s0, A-s0, B-s1, A-s1}
  auto STAGE = [&](int tIdx, int j, int dOff) {
    const size_t kof = (size_t)tIdx * 64 + (size_t)((j >> 1) << 5);
    const ushort_t* gsrc = ((j & 1) ? Ab : Bb) + kof;
    char* db = ldsc + dOff;
    load_lds16(gsrc + rb0, db + d0);
    load_lds16(gsrc + rb1, db + 8192 + d0);
  };
  auto nx = [](int x) { return (x + 16384 == 147456) ? 0 : x + 16384; };

  f32x4 acc[8][4] = {};

  // prologue: halves 0..7 (tiles 0 and 1) into regions 0..7
#pragma unroll
  for (int h = 0; h < 8; ++h) STAGE(h >> 2, h & 3, h * 16384);
  asm volatile("s_waitcnt vmcnt(8)" ::: "memory");   // tile 0 landed
  __builtin_amdgcn_s_barrier();

  int rd = 0;          // region byte of tile t's half 0
  int sOff = 131072;   // next issue region (region 8)
  for (int t = 0; t < NT; ++t) {
    const int r0 = rd, r1 = nx(r0), r2 = nx(r1), r3 = nx(r2);
    bf16x8 a[4], a2[4], b[4];
    // ---- phase q0: k-slab0, A rows m0-3 + all B
#pragma unroll
    for (int m = 0; m < 4; ++m) a[m] = *(const bf16x8*)(ldsc + r1 + offA[m]);
#pragma unroll
    for (int n = 0; n < 4; ++n) b[n] = *(const bf16x8*)(ldsc + r0 + offB[n]);
    if (t < NT - 2) { STAGE(t + 2, 0, sOff); sOff = nx(sOff); }
    __builtin_amdgcn_s_barrier();
    asm volatile("s_waitcnt lgkmcnt(0)" ::: "memory");
    __builtin_amdgcn_sched_barrier(0);
    __builtin_amdgcn_s_setprio(1);
#pragma unroll
    for (int m = 0; m < 4; ++m)
#pragma unroll
      for (int n = 0; n < 4; ++n)
        acc[m][n] = __builtin_amdgcn_mfma_f32_16x16x32_bf16(a[m], b[n], acc[m][n], 0, 0, 0);
    __builtin_amdgcn_s_setprio(0);
    __builtin_amdgcn_s_barrier();
    // ---- phase q1: k-slab0, A rows m4-7
#pragma unroll
    for (int m = 0; m < 4; ++m) a2[m] = *(const bf16x8*)(ldsc + r1 + offA[4 + m]);
    if (t < NT - 2) { STAGE(t + 2, 1, sOff); sOff = nx(sOff); }
    __builtin_amdgcn_s_barrier();
    asm volatile("s_waitcnt lgkmcnt(0)" ::: "memory");
    __builtin_amdgcn_sched_barrier(0);
    __builtin_amdgcn_s_setprio(1);
#pragma unroll
    for (int m = 0; m < 4; ++m)
#pragma unroll
      for (int n = 0; n < 4; ++n)
        acc[4 + m][n] = __builtin_amdgcn_mfma_f32_16x16x32_bf16(a2[m], b[n], acc[4 + m][n], 0, 0, 0);
    __builtin_amdgcn_s_setprio(0);
    __builtin_amdgcn_s_barrier();
    // ---- phase q2: k-slab1, A rows m0-3 + all B
#pragma unroll
    for (int m = 0; m < 4; ++m) a[m] = *(const bf16x8*)(ldsc + r3 + offA[m]);
#pragma unroll
    for (int n = 0; n < 4; ++n) b[n] = *(const bf16x8*)(ldsc + r2 + offB[n]);
    if (t < NT - 2) { STAGE(t + 2, 2, sOff); sOff = nx(sOff); }
    __builtin_amdgcn_s_barrier();
    asm volatile("s_waitcnt lgkmcnt(0)" ::: "memory");
    __builtin_amdgcn_sched_barrier(0);
    __builtin_amdgcn_s_setprio(1);
#pragma unroll
    for (int m = 0; m < 4; ++m)
#pragma unroll
      for (int n = 0; n < 4; ++n)
        acc[m][n] = __builtin_amdgcn_mfma_f32_16x16x32_bf16(a[m], b[n], acc[m][n], 0, 0, 0);
    __builtin_amdgcn_s_setprio(0);
    __builtin_amdgcn_s_barrier();
    // ---- phase q3: k-slab1, A rows m4-7
#pragma unroll
    for (int m = 0; m < 4; ++m) a2[m] = *(const bf16x8*)(ldsc + r3 + offA[4 + m]);
    if (t < NT - 2) { STAGE(t + 2, 3, sOff); sOff = nx(sOff); }
    __builtin_amdgcn_s_barrier();
    asm volatile("s_waitcnt lgkmcnt(0)" ::: "memory");
    __builtin_amdgcn_sched_barrier(0);
    __builtin_amdgcn_s_setprio(1);
#pragma unroll
    for (int m = 0; m < 4; ++m)
#pragma unroll
      for (int n = 0; n < 4; ++n)
        acc[4 + m][n] = __builtin_amdgcn_mfma_f32_16x16x32_bf16(a2[m], b[n], acc[4 + m][n], 0, 0, 0);
    __builtin_amdgcn_s_setprio(0);
    // tile-end: prove tile t+1 landed BEFORE crossing the barrier
    if (t < NT - 2)       asm volatile("s_waitcnt vmcnt(6)" ::: "memory");
    else if (t == NT - 2) asm volatile("s_waitcnt vmcnt(0)" ::: "memory");
    __builtin_amdgcn_s_barrier();
    rd = nx(r3);
  }

  // epilogue: C/D layout col=lane&15, row=(lane>>4)*4+reg
#pragma unroll
  for (int m = 0; m < 8; ++m) {
#pragma unroll
    for (int n = 0; n < 4; ++n) {
      size_t gm = m0 + wm * 128 + m * 16 + g * 4;
      size_t gn = n0 + wn * 64 + n * 16 + c;
      float bn = bias[gn];
#pragma unroll
      for (int r = 0; r < 4; ++r) {
        float v = acc[m][n][r] + bn;
        if (OUT_F32) ((float*)Cout)[(gm + r) * (size_t)N + gn] = v;
        else         ((ushort_t*)Cout)[(gm + r) * (size_t)N + gn] = f2bf(v);
      }
    }
  }
  (void)M;
}

// ---------------- 128x128 GEMM (m97 structure) for the small KV GEMM ----------------
template <int OUT_F32>
__global__ __launch_bounds__(256) void gemm_bt(const ushort_t* __restrict__ A,
                                               const ushort_t* __restrict__ W,
                                               const float* __restrict__ bias,
                                               void* __restrict__ Cout,
                                               int M, int N, int K) {
  __shared__ ushort_t sA[128 * 32];
  __shared__ ushort_t sB[128 * 32];
  const int tid = threadIdx.x;
  const int w = tid >> 6, lane = tid & 63;
  const int g = lane >> 4, c = lane & 15;
  const int ntn = N >> 7;
  const int nwg = gridDim.x;
  int bid = blockIdx.x;
  bid = (bid & 7) * (nwg >> 3) + (bid >> 3);
  const int tm = bid / ntn, tn = bid % ntn;
  const size_t m0 = (size_t)tm * 128, n0 = (size_t)tn * 128;
  const int wr = (w >> 1) * 64, wc = (w & 1) * 64;

  f32x4 acc[4][4] = {};

  const ushort_t* Abase = A + m0 * (size_t)K;
  const ushort_t* Bbase = W + n0 * (size_t)K;

  for (int k0 = 0; k0 < K; k0 += 32) {
    __syncthreads();
#pragma unroll
    for (int i = 0; i < 2; ++i) {
      int gid = i * 256 + tid;
      int row = gid >> 2, colE = (gid & 3) << 3;
      load_lds16(Abase + (size_t)row * K + k0 + colE, sA + i * 2048 + w * 512);
      load_lds16(Bbase + (size_t)row * K + k0 + colE, sB + i * 2048 + w * 512);
    }
    __syncthreads();
    bf16x8 a[4], b[4];
#pragma unroll
    for (int m = 0; m < 4; ++m)
      a[m] = *(const bf16x8*)(sA + (wr + m * 16 + c) * 32 + g * 8);
#pragma unroll
    for (int n = 0; n < 4; ++n)
      b[n] = *(const bf16x8*)(sB + (wc + n * 16 + c) * 32 + g * 8);
#pragma unroll
    for (int m = 0; m < 4; ++m)
#pragma unroll
      for (int n = 0; n < 4; ++n)
        acc[m][n] = __builtin_amdgcn_mfma_f32_16x16x32_bf16(a[m], b[n], acc[m][n], 0, 0, 0);
  }

#pragma unroll
  for (int m = 0; m < 4; ++m) {
#pragma unroll
    for (int n = 0; n < 4; ++n) {
      size_t gm = m0 + wr + m * 16 + g * 4;
      size_t gn = n0 + wc + n * 16 + c;
      float bn = bias[gn];
#pragma unroll
      for (int r = 0; r < 4; ++r) {
        float v = acc[m][n][r] + bn;
        if (OUT_F32) ((float*)Cout)[(gm + r) * (size_t)N + gn] = v;
        else         ((ushort_t*)Cout)[(gm + r) * (size_t)N + gn] = f2bf(v);
      }
    }
  }
}

// ---------------- RMSNorm (in place; optional extra output scale) ----------------
__global__ __launch_bounds__(256) void rmsnorm_rows(ushort_t* __restrict__ x,
                                                    const float* __restrict__ gw,
                                                    int ncols, int stride, float oscale) {
  const int row = blockIdx.x;
  ushort_t* p = x + (size_t)row * stride;
  const int tid = threadIdx.x;
  const int nch = ncols >> 3;
  float ss = 0.f;
  for (int ci = tid; ci < nch; ci += 256) {
    bf16x8 v = *(const bf16x8*)(p + ci * 8);
#pragma unroll
    for (int j = 0; j < 8; ++j) { float f = (float)v[j]; ss += f * f; }
  }
#pragma unroll
  for (int off = 1; off < 64; off <<= 1) ss += __shfl_xor(ss, off);
  __shared__ float sred[4];
  if ((tid & 63) == 0) sred[tid >> 6] = ss;
  __syncthreads();
  float tot = sred[0] + sred[1] + sred[2] + sred[3];
  float inv = rsqrtf(tot / (float)ncols + 1e-6f) * oscale;
  for (int ci = tid; ci < nch; ci += 256) {
    bf16x8 v = *(const bf16x8*)(p + ci * 8);
    bf16x8 ov;
#pragma unroll
    for (int j = 0; j < 8; ++j) {
      float f = (float)v[j];
      ushort_t ob = f2bf(f * inv * gw[ci * 8 + j]);
      ov[j] = *(__bf16*)&ob;
    }
    *(bf16x8*)(p + ci * 8) = ov;
  }
}

// ---------------- V transpose: kv[:, DIM + h*HD + d] -> vt[bh][d][l] ----------------
__global__ __launch_bounds__(256) void transpose_v(const ushort_t* __restrict__ kv,
                                                   ushort_t* __restrict__ vt) {
  const int bh = blockIdx.y, b = bh / NH, h = bh % NH;
  const int l0 = blockIdx.x * 32;
  const ushort_t* src = kv + (size_t)b * L_LEN * (2 * DIM) + DIM + (size_t)h * HD;
  ushort_t* dst = vt + (size_t)bh * HD * L_LEN;
  __shared__ ushort_t tile[32][HD + 16];
  const int tid = threadIdx.x;
#pragma unroll
  for (int i = 0; i < 2; ++i) {
    int gid = i * 256 + tid;
    int r = gid >> 4, ce = (gid & 15) << 3;
    *(bf16x8*)(&tile[r][ce]) = *(const bf16x8*)(src + (size_t)(l0 + r) * (2 * DIM) + ce);
  }
  __syncthreads();
#pragma unroll
  for (int i = 0; i < 2; ++i) {
    int gid = i * 256 + tid;
    int d = gid >> 2, le = (gid & 3) << 3;
    bf16x8 v;
#pragma unroll
    for (int j = 0; j < 8; ++j) v[j] = *(__bf16*)&tile[le + j][d];
    *(bf16x8*)(dst + (size_t)d * L_LEN + l0 + le) = v;
  }
}

// ---------------- fused cross-attention (swapped-QK^T, in-register softmax) ----------
__global__ __launch_bounds__(256) void attn_fwd(const ushort_t* __restrict__ q,
                                                const ushort_t* __restrict__ kv,
                                                const ushort_t* __restrict__ vt,
                                                ushort_t* __restrict__ out) {
  const int bh = blockIdx.y, b = bh / NH, h = bh % NH;
  const int tid = threadIdx.x, w = tid >> 6, lane = tid & 63;
  const int lq = lane & 31, hi = lane >> 5;
  const int qr0 = blockIdx.x * 128 + w * 32;

  const ushort_t* qrow  = q  + ((size_t)b * S_LEN + qr0 + lq) * DIM + (size_t)h * HD + hi * 8;
  const ushort_t* krow  = kv + (size_t)b * L_LEN * (2 * DIM) + (size_t)h * HD
                             + (size_t)lq * (2 * DIM) + hi * 8;
  const ushort_t* vrow  = vt + (size_t)bh * HD * L_LEN + (size_t)lq * L_LEN + hi * 8;

  bf16x8 qf[8];
#pragma unroll
  for (int ks = 0; ks < 8; ++ks) qf[ks] = *(const bf16x8*)(qrow + ks * 16);

  f32x16 o[4];
#pragma unroll
  for (int ch = 0; ch < 4; ++ch) o[ch] = 0.f;
  float m = -1e30f, lsum = 0.f;

  for (int l0 = 0; l0 < L_LEN; l0 += 32) {
    f32x16 sv = 0.f;
#pragma unroll
    for (int ks = 0; ks < 8; ++ks) {
      bf16x8 kf = *(const bf16x8*)(krow + (size_t)l0 * (2 * DIM) + ks * 16);
      sv = __builtin_amdgcn_mfma_f32_32x32x16_bf16(kf, qf[ks], sv, 0, 0, 0);
    }
    float pm = fmaxf(fmaxf(fmaxf(sv[0], sv[1]), fmaxf(sv[2], sv[3])),
                     fmaxf(fmaxf(sv[4], sv[5]), fmaxf(sv[6], sv[7])));
    pm = fmaxf(pm, fmaxf(fmaxf(fmaxf(sv[8], sv[9]), fmaxf(sv[10], sv[11])),
                         fmaxf(fmaxf(sv[12], sv[13]), fmaxf(sv[14], sv[15]))));
    pm = fmaxf(pm, __shfl_xor(pm, 32));
    if (__ballot(pm > m + 8.0f)) {
      float mn = fmaxf(m, pm);
      float al = __builtin_amdgcn_exp2f(m - mn);
      lsum *= al;
      m = mn;
#pragma unroll
      for (int r = 0; r < 16; ++r) {
        float ar = __shfl(al, (r & 3) + 8 * (r >> 2) + 4 * hi);
        o[0][r] *= ar; o[1][r] *= ar; o[2][r] *= ar; o[3][r] *= ar;
      }
    }
    float p[16]; float ls = 0.f;
#pragma unroll
    for (int r = 0; r < 16; ++r) { p[r] = __builtin_amdgcn_exp2f(sv[r] - m); ls += p[r]; }
    ls += __shfl_xor(ls, 32);
    lsum += ls;
    bf16x8 pa[2];
#pragma unroll
    for (int ks = 0; ks < 2; ++ks) {
      unsigned w0 = (unsigned)f2bf(p[8 * ks + 0]) | ((unsigned)f2bf(p[8 * ks + 1]) << 16);
      unsigned w1 = (unsigned)f2bf(p[8 * ks + 2]) | ((unsigned)f2bf(p[8 * ks + 3]) << 16);
      unsigned w2 = (unsigned)f2bf(p[8 * ks + 4]) | ((unsigned)f2bf(p[8 * ks + 5]) << 16);
      unsigned w3 = (unsigned)f2bf(p[8 * ks + 6]) | ((unsigned)f2bf(p[8 * ks + 7]) << 16);
      unsigned e0 = __shfl_xor((int)w0, 32), e1 = __shfl_xor((int)w1, 32);
      unsigned e2 = __shfl_xor((int)w2, 32), e3 = __shfl_xor((int)w3, 32);
      unsigned d0 = hi ? e2 : w0, d1 = hi ? e3 : w1;
      unsigned d2 = hi ? w2 : e0, d3 = hi ? w3 : e1;
      unsigned tmp[4] = {d0, d1, d2, d3};
      pa[ks] = *(const bf16x8*)tmp;
    }
#pragma unroll
    for (int ch = 0; ch < 4; ++ch) {
#pragma unroll
      for (int ks = 0; ks < 2; ++ks) {
        bf16x8 vf = *(const bf16x8*)(vrow + (size_t)ch * 32 * L_LEN + l0 + ks * 16);
        o[ch] = __builtin_amdgcn_mfma_f32_32x32x16_bf16(pa[ks], vf, o[ch], 0, 0, 0);
      }
    }
  }

  float inv[16];
#pragma unroll
  for (int r = 0; r < 16; ++r) {
    float lr = __shfl(lsum, (r & 3) + 8 * (r >> 2) + 4 * hi);
    inv[r] = 1.0f / lr;
  }
  ushort_t* ob = out + ((size_t)b * S_LEN + qr0) * DIM + (size_t)h * HD;
#pragma unroll
  for (int ch = 0; ch < 4; ++ch)
#pragma unroll
    for (int r = 0; r < 16; ++r) {
      int row = (r & 3) + 8 * (r >> 2) + 4 * hi;
      ob[(size_t)row * DIM + ch * 32 + lq] = f2bf(o[ch][r] * inv[r]);
    }
}

// ---------------- host ----------------
extern "C" void kernel_launch(void* const* d_in, const int* in_sizes, int n_in,
                              void* d_out, int out_size, void* d_ws, size_t ws_size,
                              hipStream_t stream) {
  (void)in_sizes; (void)n_in; (void)out_size; (void)ws_size;
  const float* hidden_c = (const float*)d_in[0];
  const float* hidden_u = (const float*)d_in[1];
  const float* ctx_c    = (const float*)d_in[2];
  const float* ctx_u    = (const float*)d_in[3];
  const float* Wq  = (const float*)d_in[4];
  const float* bq  = (const float*)d_in[5];
  const float* Wkv = (const float*)d_in[6];
  const float* bkv = (const float*)d_in[7];
  const float* gq  = (const float*)d_in[8];
  const float* gk  = (const float*)d_in[9];
  const float* Wo  = (const float*)d_in[10];
  const float* bo  = (const float*)d_in[11];

  char* ws = (char*)d_ws;
  size_t off = 0;
  auto alloc = [&](size_t bytes) {
    char* p = ws + off; off += (bytes + 255) & ~(size_t)255; return p;
  };
  ushort_t* hbf  = (ushort_t*)alloc((size_t)MQ * DIM * 2);
  ushort_t* cbf  = (ushort_t*)alloc((size_t)ML * DIM * 2);
  ushort_t* wqb  = (ushort_t*)alloc((size_t)DIM * DIM * 2);
  ushort_t* wkvb = (ushort_t*)alloc((size_t)2 * DIM * DIM * 2);
  ushort_t* kvb  = (ushort_t*)alloc((size_t)ML * 2 * DIM * 2);
  ushort_t* vtb  = (ushort_t*)alloc((size_t)CBATCH * NH * HD * L_LEN * 2);
  ushort_t* qb   = (ushort_t*)d_out;

  auto cvt = [&](const float* in, ushort_t* o, size_t n) {
    int n4 = (int)(n >> 2);
    cvt_f32_bf16<<<dim3((n4 + 255) / 256), dim3(256), 0, stream>>>(in, o, n4);
  };
  cvt(hidden_c, hbf, (size_t)S_LEN * DIM);
  cvt(hidden_u, hbf + (size_t)S_LEN * DIM, (size_t)S_LEN * DIM);
  cvt(ctx_c, cbf, (size_t)L_LEN * DIM);
  cvt(ctx_u, cbf + (size_t)L_LEN * DIM, (size_t)L_LEN * DIM);
  cvt(Wq, wqb, (size_t)DIM * DIM);
  cvt(Wkv, wkvb, (size_t)2 * DIM * DIM);

  // Q = hidden @ Wq^T + bq  (256x256 tiles, 9-region ring)
  gemm_bt8<0><<<dim3((MQ / 256) * (DIM / 256)), dim3(512), 0, stream>>>(
      hbf, wqb, bq, (void*)qb, MQ, DIM, DIM);
  // KV = context @ Wkv^T + bkv   [128x128]
  gemm_bt<0><<<dim3((ML / 128) * ((2 * DIM) / 128)), dim3(256), 0, stream>>>(
      cbf, wkvb, bkv, (void*)kvb, ML, 2 * DIM, DIM);
  cvt(Wo, wqb, (size_t)DIM * DIM);

  const float qscale = 0.08838834764831845f * 1.4426950408889634f;
  rmsnorm_rows<<<dim3(MQ), dim3(256), 0, stream>>>(qb, gq, DIM, DIM, qscale);
  rmsnorm_rows<<<dim3(ML), dim3(256), 0, stream>>>(kvb, gk, DIM, 2 * DIM, 1.0f);
  transpose_v<<<dim3(L_LEN / 32, CBATCH * NH), dim3(256), 0, stream>>>(kvb, vtb);

  attn_fwd<<<dim3(S_LEN / 128, CBATCH * NH), dim3(256), 0, stream>>>(qb, kvb, vtb, hbf);

  // out = attn_out @ Wo^T + bo -> d_out (fp32)
  gemm_bt8<1><<<dim3((MQ / 256) * (DIM / 256)), dim3(512), 0, stream>>>(
      hbf, wqb, bo, d_out, MQ, DIM, DIM);
}